// Round 1
// baseline (972.676 us; speedup 1.0000x reference)
//
#include <hip/hip_runtime.h>

#define HH 192
#define WW 192

typedef __attribute__((ext_vector_type(8))) short bf16x8;
typedef __attribute__((ext_vector_type(4))) float f32x4;

__device__ __forceinline__ unsigned short f2bf(float f) {
    unsigned u = __builtin_bit_cast(unsigned, f);
    return (unsigned short)((u + 0x7FFFu + ((u >> 16) & 1u)) >> 16);
}

// Fuse the 5 weight tensors into one effective 3x3 bf16 kernel, stored
// fragment-linear for mfma_f32_16x16x32_bf16 A-operand (A[row=o][k=c32]):
//   wbuf[(((cc*9 + tap)*8 + ot)*64 + lane)*8 + j]
//   cc = c>>5, ot = o>>4, lane = ((c>>3)&3)*16 + (o&15), j = c&7
__global__ void fuse_weights(const float* __restrict__ wsq, const float* __restrict__ wv,
                             const float* __restrict__ whr, const float* __restrict__ w19,
                             const float* __restrict__ w37, unsigned short* __restrict__ wbuf) {
    int idx = blockIdx.x * 256 + threadIdx.x;
    if (idx >= 128 * 128 * 9) return;
    int o = idx / 1152;
    int r = idx - o * 1152;
    int c = r / 9;
    int tap = r - c * 9;
    int kh = tap / 3, kw = tap - kh * 3;
    float v = wsq[((o * 128 + c) * 3 + kh) * 3 + kw];
    if (kw == 1) v += wv[(o * 128 + c) * 3 + kh];          // 3x1, pad (1,1),(0,0) == center col
    if (kh == 1) v += whr[(o * 128 + c) * 3 + kw];         // 1x3, pad (0,0),(1,1) == center row
    if (kh == kw) v += w19[((o * 128 + c) * 3 + kh) * 3 + kw];       // eye mask
    if (kh + kw == 2) v += w37[((o * 128 + c) * 3 + kh) * 3 + kw];   // anti-eye mask
    int cc = c >> 5, ot = o >> 4;
    int ln = ((c >> 3) & 3) * 16 + (o & 15);
    int j = c & 7;
    wbuf[(((cc * 9 + tap) * 8 + ot) * 64 + ln) * 8 + j] = f2bf(v);
}

// One block = 16x16 output tile (one image), all 128 output channels.
// 4 waves: wave = (mi: o-half, ni: row-half). Per wave: 4 o-frags x 8 row-frags.
// K-loop: 4 c-chunks of 32; input chunk staged NCHW->LDS bf16 [pix 18x18][c 32],
// pixel stride 80B (64B data + 16B pad -> conflict-free-ish banks).
__global__ __launch_bounds__(256) void conv3x3(const float* __restrict__ x,
                                               const unsigned short* __restrict__ wbuf,
                                               float* __restrict__ out) {
    __shared__ __align__(16) unsigned char lds[324 * 80];
    const int t = threadIdx.x;
    const int lane = t & 63;
    const int wvid = t >> 6;
    const int mi = wvid >> 1;   // o half
    const int ni = wvid & 1;    // output-row half
    const int l15 = lane & 15;
    const int l4 = lane >> 4;

    const int b = blockIdx.z;
    const int h0 = blockIdx.y * 16;
    const int w0 = blockIdx.x * 16;

    const float* __restrict__ xb = x + (size_t)b * (128 * HH * WW);

    f32x4 acc[4][8];
    const f32x4 zero = {0.f, 0.f, 0.f, 0.f};
#pragma unroll
    for (int mo = 0; mo < 4; ++mo)
#pragma unroll
        for (int np = 0; np < 8; ++np)
            acc[mo][np] = zero;

    // staging: chunk = 32c x 18h x 18w = 10368 elems; thread t walks e = t + 256*it
    const int ih_init = t / 18;
    const int iw_init = t - ih_init * 18;
    const int lane_term = l15 * 80 + l4 * 16;

#pragma unroll 1
    for (int cc = 0; cc < 4; ++cc) {
        { // ---- stage chunk cc into LDS ----
            int c_local = 0, ih = ih_init, iw = iw_init;
#pragma unroll 1
            for (int it = 0; it < 41; ++it) {
                if (it < 40 || t < 128) {
                    int gh = h0 - 1 + ih;
                    int gw = w0 - 1 + iw;
                    float v = 0.f;
                    if ((unsigned)gh < HH && (unsigned)gw < WW)
                        v = xb[(size_t)(cc * 32 + c_local) * (HH * WW) + gh * WW + gw];
                    *(unsigned short*)(lds + (ih * 18 + iw) * 80 + c_local * 2) = f2bf(v);
                }
                // advance flat index by 256: 256 = 14*18 + 4
                iw += 4; ih += 14;
                if (iw >= 18) { iw -= 18; ih += 1; }
                if (ih >= 18) { ih -= 18; c_local += 1; }
            }
        }
        __syncthreads();

        // ---- compute: 9 taps x (4 o-frags x 8 row-frags) MFMA ----
        const unsigned short* wp0 = wbuf + ((size_t)(cc * 9) * 8 + mi * 4) * 512 + lane * 8;
        bf16x8 a_cur[4], a_nxt[4];
#pragma unroll
        for (int mo = 0; mo < 4; ++mo)
            a_cur[mo] = *(const bf16x8*)(wp0 + mo * 512);

        int kh = 0, kw = 0;
#pragma unroll 1
        for (int tap = 0; tap < 9; ++tap) {
            if (tap < 8) {  // prefetch next tap's weight frags (L2-resident)
                const unsigned short* wp = wp0 + (size_t)(tap + 1) * 4096;
#pragma unroll
                for (int mo = 0; mo < 4; ++mo)
                    a_nxt[mo] = *(const bf16x8*)(wp + mo * 512);
            }
            const int base = (ni * 8 + kh) * 1440 + kw * 80 + lane_term;
#pragma unroll
            for (int np = 0; np < 8; ++np) {
                bf16x8 bf = *(const bf16x8*)(lds + base + np * 1440);
#pragma unroll
                for (int mo = 0; mo < 4; ++mo)
                    acc[mo][np] = __builtin_amdgcn_mfma_f32_16x16x32_bf16(a_cur[mo], bf, acc[mo][np], 0, 0, 0);
            }
#pragma unroll
            for (int mo = 0; mo < 4; ++mo)
                a_cur[mo] = a_nxt[mo];
            kw += 1; if (kw == 3) { kw = 0; kh += 1; }
        }
        __syncthreads();
    }

    // ---- epilogue: D row=(l>>4)*4+j -> o, col=l&15 -> w  (coalesced 64B rows) ----
    float* __restrict__ ob = out + (size_t)b * (128 * HH * WW) + (size_t)h0 * WW + w0 + l15;
#pragma unroll
    for (int mo = 0; mo < 4; ++mo) {
#pragma unroll
        for (int j = 0; j < 4; ++j) {
            int o = mi * 64 + mo * 16 + l4 * 4 + j;
            float* op = ob + (size_t)o * (HH * WW);
#pragma unroll
            for (int np = 0; np < 8; ++np)
                op[(ni * 8 + np) * WW] = acc[mo][np][j];
        }
    }
}

extern "C" void kernel_launch(void* const* d_in, const int* in_sizes, int n_in,
                              void* d_out, int out_size, void* d_ws, size_t ws_size,
                              hipStream_t stream) {
    const float* x   = (const float*)d_in[0];
    const float* wsq = (const float*)d_in[1];
    const float* wv  = (const float*)d_in[2];
    const float* wh  = (const float*)d_in[3];
    const float* w19 = (const float*)d_in[4];
    const float* w37 = (const float*)d_in[5];
    unsigned short* wbuf = (unsigned short*)d_ws;  // 294,912 B

    fuse_weights<<<576, 256, 0, stream>>>(wsq, wv, wh, w19, w37, wbuf);

    dim3 grid(WW / 16, HH / 16, 16);  // 12 x 12 x 16 = 2304 blocks
    conv3x3<<<grid, 256, 0, stream>>>(x, wbuf, (float*)d_out);
}

// Round 2
// 385.016 us; speedup vs baseline: 2.5263x; 2.5263x over previous
//
#include <hip/hip_runtime.h>

#define HH 192
#define WW 192
#define HWPIX (HH * WW)

typedef __attribute__((ext_vector_type(8))) short bf16x8;
typedef __attribute__((ext_vector_type(8))) unsigned short u16x8;
typedef __attribute__((ext_vector_type(4))) float f32x4;

__device__ __forceinline__ unsigned short f2bf(float f) {
    unsigned u = __builtin_bit_cast(unsigned, f);
    return (unsigned short)((u + 0x7FFFu + ((u >> 16) & 1u)) >> 16);
}

__device__ __forceinline__ void gload_lds16(const void* g, void* l) {
    __builtin_amdgcn_global_load_lds((const __attribute__((address_space(1))) void*)g,
                                     (__attribute__((address_space(3))) void*)l, 16, 0, 0);
}

// ---------------- weight fusion (unchanged from round 1) ----------------
// wbuf[(((cc*9 + tap)*8 + ot)*64 + lane)*8 + j], ot=o>>4, lane=((c>>3)&3)*16+(o&15), j=c&7
__global__ void fuse_weights(const float* __restrict__ wsq, const float* __restrict__ wv,
                             const float* __restrict__ whr, const float* __restrict__ w19,
                             const float* __restrict__ w37, unsigned short* __restrict__ wbuf) {
    int idx = blockIdx.x * 256 + threadIdx.x;
    if (idx >= 128 * 128 * 9) return;
    int o = idx / 1152;
    int r = idx - o * 1152;
    int c = r / 9;
    int tap = r - c * 9;
    int kh = tap / 3, kw = tap - kh * 3;
    float v = wsq[((o * 128 + c) * 3 + kh) * 3 + kw];
    if (kw == 1) v += wv[(o * 128 + c) * 3 + kh];
    if (kh == 1) v += whr[(o * 128 + c) * 3 + kw];
    if (kh == kw) v += w19[((o * 128 + c) * 3 + kh) * 3 + kw];
    if (kh + kw == 2) v += w37[((o * 128 + c) * 3 + kh) * 3 + kw];
    int cc = c >> 5, ot = o >> 4;
    int ln = ((c >> 3) & 3) * 16 + (o & 15);
    int j = c & 7;
    wbuf[(((cc * 9 + tap) * 8 + ot) * 64 + ln) * 8 + j] = f2bf(v);
}

// ---------------- pass 1: NCHW fp32 -> NHWC bf16 ----------------
// block = (h, b); thread: wq = w-quad, c0 = c-octet. Reads 4x256B coalesced
// segments per inst; 16B stores merge to full lines in L2.
__global__ __launch_bounds__(256) void to_nhwc(const float* __restrict__ x,
                                               unsigned short* __restrict__ xn) {
    int h = blockIdx.x, b = blockIdx.y;
    int t = threadIdx.x;
    int wq = t & 15;
    int c0 = (t >> 4) * 8;
    const float* __restrict__ xb = x + ((size_t)b * 128 + c0) * HWPIX + h * WW;
    unsigned short* __restrict__ xnb = xn + ((size_t)(b * HH + h) * WW) * 128;
#pragma unroll 1
    for (int wc = 0; wc < 3; ++wc) {
        int w = wc * 64 + wq * 4;
        f32x4 v[8];
#pragma unroll
        for (int j = 0; j < 8; ++j)
            v[j] = *(const f32x4*)(xb + (size_t)j * HWPIX + w);
#pragma unroll
        for (int i = 0; i < 4; ++i) {
            u16x8 o;
#pragma unroll
            for (int j = 0; j < 8; ++j) o[j] = f2bf(v[j][i]);
            *(u16x8*)(xnb + (size_t)(w + i) * 128 + c0) = o;
        }
    }
}

// ---------------- pass 2: conv via MFMA, NHWC bf16 input ----------------
// Tile 16x16 out, halo 18x18, staged rows padded to 20 px (overshoot, clamped).
// c-chunk = 32 (one MFMA K), chunk = 18*20*64B = 23040 B, dbuf stride 23552.
// LDS slot swizzle: addr ^= (pix&3)<<4, applied on read and (inverse) on the
// global source so global_load_lds stays linear-dest.
#define CHUNK_B 23040
#define CHUNK_STRIDE 23552

__global__ __launch_bounds__(256) void conv_nhwc(const unsigned short* __restrict__ xn,
                                                 const unsigned short* __restrict__ wbuf,
                                                 float* __restrict__ out) {
    __shared__ __align__(1024) unsigned char lds[2 * CHUNK_STRIDE];
    const int t = threadIdx.x;
    const int l = t & 63;
    const int wv = t >> 6;
    const int mi = wv >> 1;
    const int ni = wv & 1;
    const int l15 = l & 15;
    const int l4 = l >> 4;

    const int b = blockIdx.z;
    const int h0 = blockIdx.y * 16;
    const int w0 = blockIdx.x * 16;
    const bool edge = (h0 == 0) | (h0 == HH - 16) | (w0 == 0) | (w0 == WW - 16);

    f32x4 acc[4][8];
    const f32x4 zero = {0.f, 0.f, 0.f, 0.f};
#pragma unroll
    for (int mo = 0; mo < 4; ++mo)
#pragma unroll
        for (int np = 0; np < 8; ++np) acc[mo][np] = zero;

    const size_t bpix = (size_t)b * HWPIX;

#define STAGE(CC, BB)                                                                   \
    {                                                                                   \
        _Pragma("unroll") for (int i = 0; i < 6; ++i) {                                 \
            int u = wv + 4 * i;                                                         \
            int d = u * 1024 + l * 16;                                                  \
            if (d < CHUNK_B) {                                                          \
                int dsw = d ^ ((d >> 2) & 48);                                          \
                int pix = d >> 6;                                                       \
                int slot = (dsw >> 4) & 3;                                              \
                int ih = pix / 20;                                                      \
                int iw = pix - ih * 20;                                                 \
                int gh = h0 - 1 + ih; gh = min(max(gh, 0), HH - 1);                     \
                int gw = w0 - 1 + iw; gw = min(max(gw, 0), WW - 1);                     \
                const unsigned char* src = (const unsigned char*)xn +                   \
                    (bpix + (size_t)(gh * WW + gw)) * 256 + (CC) * 64 + slot * 16;      \
                gload_lds16(src, (void*)(lds + (BB) + u * 1024));                       \
            }                                                                           \
        }                                                                               \
    }

#define ZERO_EDGES(BB)                                                                  \
    {                                                                                   \
        if (h0 == 0 && t < 80) *(f32x4*)(lds + (BB) + t * 16) = zero;                   \
        if (h0 == HH - 16 && t < 80) *(f32x4*)(lds + (BB) + 17 * 1280 + t * 16) = zero; \
        if (w0 == 0 && t < 72)                                                          \
            *(f32x4*)(lds + (BB) + (t >> 2) * 1280 + (t & 3) * 16) = zero;              \
        if (w0 == WW - 16 && t < 72)                                                    \
            *(f32x4*)(lds + (BB) + (t >> 2) * 1280 + 17 * 64 + (t & 3) * 16) = zero;    \
    }

    STAGE(0, 0);
    __syncthreads();
    if (edge) { ZERO_EDGES(0); __syncthreads(); }

    int bb = 0;
#pragma unroll 1
    for (int cc = 0; cc < 4; ++cc) {
        if (cc < 3) STAGE(cc + 1, bb ^ CHUNK_STRIDE);

        // ---- compute chunk cc from buffer bb ----
        const unsigned short* wp0 = wbuf + ((size_t)(cc * 9) * 8 + mi * 4) * 512 + l * 8;
        bf16x8 a_cur[4], a_nxt[4];
#pragma unroll
        for (int mo = 0; mo < 4; ++mo) a_cur[mo] = *(const bf16x8*)(wp0 + mo * 512);

        int kh = 0, kw = 0;
#pragma unroll 1
        for (int tap = 0; tap < 9; ++tap) {
            if (tap < 8) {
                const unsigned short* wp = wp0 + (size_t)(tap + 1) * 4096;
#pragma unroll
                for (int mo = 0; mo < 4; ++mo) a_nxt[mo] = *(const bf16x8*)(wp + mo * 512);
            }
#pragma unroll
            for (int np = 0; np < 8; ++np) {
                int pix = (ni * 8 + np + kh) * 20 + kw + l15;
                int addr = bb + pix * 64 + l4 * 16;
                addr ^= (pix & 3) << 4;
                bf16x8 bf = *(const bf16x8*)(lds + addr);
#pragma unroll
                for (int mo = 0; mo < 4; ++mo)
                    acc[mo][np] = __builtin_amdgcn_mfma_f32_16x16x32_bf16(a_cur[mo], bf, acc[mo][np], 0, 0, 0);
            }
#pragma unroll
            for (int mo = 0; mo < 4; ++mo) a_cur[mo] = a_nxt[mo];
            kw += 1; if (kw == 3) { kw = 0; kh += 1; }
        }
        __syncthreads();
        if (edge && cc < 3) { ZERO_EDGES(bb ^ CHUNK_STRIDE); __syncthreads(); }
        bb ^= CHUNK_STRIDE;
    }

    // ---- epilogue: D row=(l>>4)*4+j -> o, col=l&15 -> w ----
    float* __restrict__ ob = out + (size_t)b * (128 * HWPIX) + (size_t)h0 * WW + w0 + l15;
#pragma unroll
    for (int mo = 0; mo < 4; ++mo) {
#pragma unroll
        for (int j = 0; j < 4; ++j) {
            int o = mi * 64 + mo * 16 + l4 * 4 + j;
            float* op = ob + (size_t)o * HWPIX;
#pragma unroll
            for (int np = 0; np < 8; ++np)
                op[(ni * 8 + np) * WW] = acc[mo][np][j];
        }
    }
}

// ---------------- fallback (round-1 kernel, used if ws too small) ----------------
__global__ __launch_bounds__(256) void conv_nchw(const float* __restrict__ x,
                                                 const unsigned short* __restrict__ wbuf,
                                                 float* __restrict__ out) {
    __shared__ __align__(16) unsigned char lds[324 * 80];
    const int t = threadIdx.x;
    const int lane = t & 63;
    const int wvid = t >> 6;
    const int mi = wvid >> 1;
    const int ni = wvid & 1;
    const int l15 = lane & 15;
    const int l4 = lane >> 4;
    const int b = blockIdx.z;
    const int h0 = blockIdx.y * 16;
    const int w0 = blockIdx.x * 16;
    const float* __restrict__ xb = x + (size_t)b * (128 * HWPIX);
    f32x4 acc[4][8];
    const f32x4 zero = {0.f, 0.f, 0.f, 0.f};
#pragma unroll
    for (int mo = 0; mo < 4; ++mo)
#pragma unroll
        for (int np = 0; np < 8; ++np) acc[mo][np] = zero;
    const int ih_init = t / 18;
    const int iw_init = t - ih_init * 18;
    const int lane_term = l15 * 80 + l4 * 16;
#pragma unroll 1
    for (int cc = 0; cc < 4; ++cc) {
        {
            int c_local = 0, ih = ih_init, iw = iw_init;
#pragma unroll 1
            for (int it = 0; it < 41; ++it) {
                if (it < 40 || t < 128) {
                    int gh = h0 - 1 + ih;
                    int gw = w0 - 1 + iw;
                    float v = 0.f;
                    if ((unsigned)gh < HH && (unsigned)gw < WW)
                        v = xb[(size_t)(cc * 32 + c_local) * HWPIX + gh * WW + gw];
                    *(unsigned short*)(lds + (ih * 18 + iw) * 80 + c_local * 2) = f2bf(v);
                }
                iw += 4; ih += 14;
                if (iw >= 18) { iw -= 18; ih += 1; }
                if (ih >= 18) { ih -= 18; c_local += 1; }
            }
        }
        __syncthreads();
        const unsigned short* wp0 = wbuf + ((size_t)(cc * 9) * 8 + mi * 4) * 512 + lane * 8;
        bf16x8 a_cur[4], a_nxt[4];
#pragma unroll
        for (int mo = 0; mo < 4; ++mo) a_cur[mo] = *(const bf16x8*)(wp0 + mo * 512);
        int kh = 0, kw = 0;
#pragma unroll 1
        for (int tap = 0; tap < 9; ++tap) {
            if (tap < 8) {
                const unsigned short* wp = wp0 + (size_t)(tap + 1) * 4096;
#pragma unroll
                for (int mo = 0; mo < 4; ++mo) a_nxt[mo] = *(const bf16x8*)(wp + mo * 512);
            }
            const int base = (ni * 8 + kh) * 1440 + kw * 80 + lane_term;
#pragma unroll
            for (int np = 0; np < 8; ++np) {
                bf16x8 bf = *(const bf16x8*)(lds + base + np * 1440);
#pragma unroll
                for (int mo = 0; mo < 4; ++mo)
                    acc[mo][np] = __builtin_amdgcn_mfma_f32_16x16x32_bf16(a_cur[mo], bf, acc[mo][np], 0, 0, 0);
            }
#pragma unroll
            for (int mo = 0; mo < 4; ++mo) a_cur[mo] = a_nxt[mo];
            kw += 1; if (kw == 3) { kw = 0; kh += 1; }
        }
        __syncthreads();
    }
    float* __restrict__ ob = out + (size_t)b * (128 * HWPIX) + (size_t)h0 * WW + w0 + l15;
#pragma unroll
    for (int mo = 0; mo < 4; ++mo) {
#pragma unroll
        for (int j = 0; j < 4; ++j) {
            int o = mi * 64 + mo * 16 + l4 * 4 + j;
            float* op = ob + (size_t)o * HWPIX;
#pragma unroll
            for (int np = 0; np < 8; ++np)
                op[(ni * 8 + np) * WW] = acc[mo][np][j];
        }
    }
}

extern "C" void kernel_launch(void* const* d_in, const int* in_sizes, int n_in,
                              void* d_out, int out_size, void* d_ws, size_t ws_size,
                              hipStream_t stream) {
    const float* x   = (const float*)d_in[0];
    const float* wsq = (const float*)d_in[1];
    const float* wv  = (const float*)d_in[2];
    const float* wh  = (const float*)d_in[3];
    const float* w19 = (const float*)d_in[4];
    const float* w37 = (const float*)d_in[5];
    unsigned short* wbuf = (unsigned short*)d_ws;  // 294,912 B

    fuse_weights<<<576, 256, 0, stream>>>(wsq, wv, wh, w19, w37, wbuf);

    const size_t xn_off = 294912;
    const size_t need = xn_off + (size_t)16 * HWPIX * 128 * 2;  // 151,289,856 B
    if (ws_size >= need) {
        unsigned short* xn = (unsigned short*)((char*)d_ws + xn_off);
        to_nhwc<<<dim3(HH, 16), 256, 0, stream>>>(x, xn);
        conv_nhwc<<<dim3(WW / 16, HH / 16, 16), 256, 0, stream>>>(xn, wbuf, (float*)d_out);
    } else {
        conv_nchw<<<dim3(WW / 16, HH / 16, 16), 256, 0, stream>>>(x, wbuf, (float*)d_out);
    }
}